// Round 9
// baseline (7172.387 us; speedup 1.0000x reference)
//
#include <hip/hip_runtime.h>
#include <hip/hip_bf16.h>
#include <stdint.h>

#define T_STEPS 512
#define BATCH   256
#define HID     256

#define NRC    16      // recurrence WGs: 16 batch rows each, ALL 4 gates
#define NWWG   240     // xgemm producer WGs
#define NWG    256
#define RING   4       // ring slots
#define CHUNK  8       // time steps per chunk
#define NCHUNK 64
#define TPC    64      // tiles per chunk: (8*256/128) * (1024/256)
#define SLOT_F (CHUNK*256*1024)   // floats per ring slot (8 MB)

using short8 = __attribute__((ext_vector_type(8))) short;
using us4    = __attribute__((ext_vector_type(4))) unsigned short;
using f32x4  = __attribute__((ext_vector_type(4))) float;

#define VMCNT0() asm volatile("s_waitcnt vmcnt(0)" ::: "memory")

__device__ inline unsigned short f2bf(float f) {
  unsigned u = __float_as_uint(f);
  unsigned r = (u + 0x7fffu + ((u >> 16) & 1u)) >> 16;
  return (unsigned short)r;
}
__device__ inline float sigm(float x)   { return __builtin_amdgcn_rcpf(1.0f + __expf(-x)); }
__device__ inline float tanh_f(float x) { return 2.0f * __builtin_amdgcn_rcpf(1.0f + __expf(-2.0f * x)) - 1.0f; }

__device__ inline int ld_rlx(const int* p) {
  return __hip_atomic_load(p, __ATOMIC_RELAXED, __HIP_MEMORY_SCOPE_AGENT);
}
__device__ inline void add_rlx(int* p, int v) {
  __hip_atomic_fetch_add(p, v, __ATOMIC_RELAXED, __HIP_MEMORY_SCOPE_AGENT);
}
__device__ inline float ldg_coh(const float* p) {
  return __hip_atomic_load(p, __ATOMIC_RELAXED, __HIP_MEMORY_SCOPE_AGENT);
}
__device__ inline void stg_coh(float* p, float v) {
  __hip_atomic_store(p, v, __ATOMIC_RELAXED, __HIP_MEMORY_SCOPE_AGENT);
}

// h LDS swizzle (proven r5/r7): XOR bits 4..5 with bits 8..9; preserves 8B/16B runs
__device__ inline int hswz(int byte) { return byte ^ (((byte >> 8) & 3) << 4); }

struct RecSm {
  unsigned short hL[4096];      // 8 KB frag-linear h (16 batch x 256 k, bf16)
  float z[16][1028];            // 65.8 KB z staging (+4 pad)
  int rdy;
};
struct GemSm { unsigned short aL[4096]; unsigned short bL[8192]; };

// ---------------- prep: pack weights + zero flags ----------------
// Wfull : [1024 cols][768 k] bf16 (k 0..511 = x part, 512..767 = h part)
__global__ __launch_bounds__(256) void prep_kernel(
    const float* __restrict__ Wf, const float* __restrict__ Wi,
    const float* __restrict__ Wg, const float* __restrict__ Wo,
    const float* __restrict__ bf_, const float* __restrict__ bi_,
    const float* __restrict__ bg_, const float* __restrict__ bo_,
    const float* __restrict__ thf, const float* __restrict__ thi,
    const float* __restrict__ thg, const float* __restrict__ tho,
    unsigned short* __restrict__ Wfull, float* __restrict__ cvec,
    int* __restrict__ flags)
{
  int j = blockIdx.x;            // 0..1023 output col
  int g = j >> 8, col = j & 255;
  const float* W  = (g==0)?Wf:(g==1)?Wi:(g==2)?Wg:Wo;
  const float* bb = (g==0)?bf_:(g==1)?bi_:(g==2)?bg_:bo_;
  const float* th = (g==0)?thf:(g==1)?thi:(g==2)?thg:tho;
  const float* wrow = W + (size_t)col * 768;
  for (int k = threadIdx.x; k < 768; k += blockDim.x)
    Wfull[(size_t)j * 768 + k] = f2bf(wrow[k]);
  if (threadIdx.x == 0) cvec[j] = bb[col] + th[col];
  if (j == 0) for (int i = threadIdx.x; i < 512; i += 256) flags[i] = 0;
}

// ---------------- persistent kernel ----------------
// blocks 0..15   : recurrence, rows bid*16..+15, all gates, Wh streamed from L2
// blocks 16..255 : xgemm producers filling the Zx ring
__global__ __launch_bounds__(512, 2) void persist_kernel(
    const float* __restrict__ X,
    const unsigned short* __restrict__ Wfull,
    const float* __restrict__ cvec,
    float* __restrict__ ring,
    int* __restrict__ done,       // [64]
    int* __restrict__ consumed,   // [1]
    float* __restrict__ out)
{
  __shared__ union { RecSm rec; GemSm gem; } sm;

  int bid = blockIdx.x, tid = threadIdx.x;
  int lane = tid & 63, wv = tid >> 6;       // 8 waves
  int l15 = lane & 15, lk = lane >> 4;

  if (bid < NRC) {
    // ================= recurrence: no cross-WG exchange =================
    int bg = bid;
    int cs = wv * 128;                       // this wave's gate-col strip
    int r0 = wv * 2;                         // this wave's 2 batch rows (local)

    for (int i = tid; i < 4096; i += 512) sm.rec.hL[i] = 0;
    if (tid == 0) sm.rec.rdy = 0;

    f32x4 cr[2] = {(f32x4){0.f,0.f,0.f,0.f}, (f32x4){0.f,0.f,0.f,0.f}};
    __syncthreads();

    for (int t = 0; t < T_STEPS; ++t) {
      int cIdx = t >> 3;

      // ---- (A) chunk gate (speculated) ----
      if ((t & 7) == 0) {
        if (sm.rec.rdy < TPC) {
          if (tid == 0) { while (ld_rlx(&done[cIdx]) < TPC) __builtin_amdgcn_s_sleep(1); }
          __syncthreads();
        }
      }

      // ---- (B) first A-frags (L2), then zx issue (LLC; used ~2500cy later) ----
      short8 aA[8], aB[8];
#pragma unroll
      for (int ct = 0; ct < 8; ++ct)
        aA[ct] = *(const short8*)(Wfull + (size_t)(cs + ct*16 + l15)*768 + 512 + lk*8);

      const float* slot = ring + (size_t)(cIdx & (RING-1))*SLOT_F
                        + (size_t)(t & 7)*256*1024;
      float zx[2][4][4];
#pragma unroll
      for (int r = 0; r < 2; ++r) {
        const float* zp = slot + (size_t)(bg*16 + r0 + r)*1024 + 4*lane;
#pragma unroll
        for (int g = 0; g < 4; ++g)
#pragma unroll
          for (int j = 0; j < 4; ++j)
            zx[r][g][j] = ldg_coh(zp + g*256 + j);
      }

      // B-frags: h(t-1) from LDS (broadcast across waves)
      short8 hb[8];
#pragma unroll
      for (int kk = 0; kk < 8; ++kk)
        hb[kk] = *(const short8*)((const char*)sm.rec.hL + hswz(kk*1024 + lane*16));

      // ---- (C) MFMA: 8 col-tiles x 8 k-tiles, A streamed from L2 ----
      f32x4 acc[8];
#pragma unroll
      for (int ct = 0; ct < 8; ++ct) acc[ct] = (f32x4){0.f,0.f,0.f,0.f};
#pragma unroll
      for (int kk = 0; kk < 8; ++kk) {
        short8* ac = (kk & 1) ? aB : aA;
        short8* an = (kk & 1) ? aA : aB;
        if (kk < 7) {
#pragma unroll
          for (int ct = 0; ct < 8; ++ct)
            an[ct] = *(const short8*)(Wfull + (size_t)(cs + ct*16 + l15)*768 + 512 + (kk+1)*32 + lk*8);
        }
#pragma unroll
        for (int ct = 0; ct < 8; ++ct)
          acc[ct] = __builtin_amdgcn_mfma_f32_16x16x32_bf16(ac[ct], hb[kk], acc[ct], 0, 0, 0);
      }
      // D: col(batch)=l15, row(gate-col)=lk*4+q  -> z[batch][gatecol]
#pragma unroll
      for (int ct = 0; ct < 8; ++ct)
        *(f32x4*)&sm.rec.z[l15][cs + ct*16 + lk*4] = acc[ct];
      __syncthreads();   // (D)

      // ---- (E) scan: lane owns cols 4L..4L+3 per gate; 2 rows ----
      float vv[2][4][4];
#pragma unroll
      for (int r = 0; r < 2; ++r)
#pragma unroll
        for (int g = 0; g < 4; ++g) {
          f32x4 zz = *(const f32x4*)&sm.rec.z[r0 + r][g*256 + 4*lane];
#pragma unroll
          for (int j = 0; j < 4; ++j)
            vv[r][g][j] = __cosf(zz[j] + zx[r][g][j]);
        }
      float S[8];
#pragma unroll
      for (int k = 0; k < 8; ++k) {
        int r = k >> 2, g = k & 3;
        S[k] = vv[r][g][0]*vv[r][g][1]*vv[r][g][2]*vv[r][g][3];
      }
#pragma unroll
      for (int off = 1; off < 64; off <<= 1) {
        float u[8];
#pragma unroll
        for (int k = 0; k < 8; ++k) u[k] = __shfl_up(S[k], (unsigned)off, 64);
        if (lane >= off) {
#pragma unroll
          for (int k = 0; k < 8; ++k) S[k] *= u[k];
        }
      }
      float E[8];
#pragma unroll
      for (int k = 0; k < 8; ++k) {
        float e = __shfl_up(S[k], 1u, 64);
        E[k] = (lane == 0) ? 1.0f : e;
      }

      float av[2][4][4];
#pragma unroll
      for (int r = 0; r < 2; ++r)
#pragma unroll
        for (int g = 0; g < 4; ++g) {
          int k = r*4 + g;
          float o0 = E[k]*vv[r][g][0];
          float o1 = o0  *vv[r][g][1];
          float o2 = o1  *vv[r][g][2];
          float o3 = o2  *vv[r][g][3];
          if (g == 2) { av[r][g][0]=tanh_f(o0); av[r][g][1]=tanh_f(o1);
                        av[r][g][2]=tanh_f(o2); av[r][g][3]=tanh_f(o3); }
          else        { av[r][g][0]=sigm(o0);   av[r][g][1]=sigm(o1);
                        av[r][g][2]=sigm(o2);   av[r][g][3]=sigm(o3); }
        }

      // ---- (F) LSTM update, h -> LDS + out ----
#pragma unroll
      for (int r = 0; r < 2; ++r) {
        float hv[4];
#pragma unroll
        for (int j = 0; j < 4; ++j) {
          float cn = av[r][0][j]*cr[r][j] + av[r][1][j]*av[r][2][j];
          cr[r][j] = cn;
          hv[j] = av[r][3][j]*tanh_f(cn);
        }
        int k = 4*lane;
        int byte = (k >> 5)*1024 + ((k >> 3) & 3)*256 + (r0 + r)*16 + (k & 7)*2;
        us4 hp = { f2bf(hv[0]), f2bf(hv[1]), f2bf(hv[2]), f2bf(hv[3]) };
        *(us4*)((char*)sm.rec.hL + hswz(byte)) = hp;
        int brow = bg*16 + r0 + r;
        f32x4 ho = { hv[0], hv[1], hv[2], hv[3] };
        *(f32x4*)&out[(size_t)t*(BATCH*HID) + (size_t)brow*256 + 4*lane] = ho;
        if (t == T_STEPS-1) {
          *(f32x4*)&out[(size_t)T_STEPS*(BATCH*HID) + (size_t)brow*256 + 4*lane] = ho;
          *(f32x4*)&out[(size_t)T_STEPS*(BATCH*HID) + BATCH*HID + (size_t)brow*256 + 4*lane] = cr[r];
        }
      }

      // ---- (G) speculation + consumed ----
      if (tid == 0) sm.rec.rdy = ld_rlx(&done[cIdx + 1]);
      if ((t & 7) == 7 && tid == 0) add_rlx(consumed, 1);
      __syncthreads();   // (H) hL(t) complete; z/rdy reads done
    }
  } else {
    // ================= xgemm producers (proven r5 code; 128x256 tiles) =========
    int w0 = bid - NRC;
    int wr = wv >> 2, wc = wv & 3;          // 2 x 4 wave grid, 64x64 per wave
    int rA = tid >> 2, kA = (tid & 3) * 8;  // A staging: 128 rows x 32 k
    int rB = tid >> 1, kB = (tid & 1) * 16; // B staging: 256 cols x 32 k

    for (int gt = w0; gt < NCHUNK * TPC; gt += NWWG) {
      int c  = gt >> 6;
      int tl = gt & 63;
      int tm = tl >> 2, tn = tl & 3;

      int need = NRC * (c - RING + 1);
      if (need > 0) {
        if (tid == 0) { while (ld_rlx(consumed) < need) __builtin_amdgcn_s_sleep(8); }
        __syncthreads();
      }

      const float* Xb = X + ((size_t)c*(CHUNK*256) + (size_t)tm*128) * 512;
      float* slotp = ring + (size_t)(c & (RING-1)) * SLOT_F;

      f32x4 acc[4][4];
#pragma unroll
      for (int mi = 0; mi < 4; ++mi)
#pragma unroll
        for (int ni = 0; ni < 4; ++ni) acc[mi][ni] = (f32x4){0.f,0.f,0.f,0.f};

      int slotA = (rA >> 4)*1024 + ((tid & 3)*16 + (rA & 15))*16;
      int baseB = (rB >> 4)*1024;
      int kO = kB >> 3;
      int slotB0 = baseB + ((kO    )*16 + (rB & 15))*16;
      int slotB1 = baseB + ((kO + 1)*16 + (rB & 15))*16;

      for (int kb = 0; kb < 512; kb += 32) {
        const float* ap = Xb + (size_t)rA*512 + kb + kA;
        f32x4 v0 = *(const f32x4*)ap;
        f32x4 v1 = *(const f32x4*)(ap + 4);
        unsigned short t8[8];
        t8[0]=f2bf(v0[0]); t8[1]=f2bf(v0[1]); t8[2]=f2bf(v0[2]); t8[3]=f2bf(v0[3]);
        t8[4]=f2bf(v1[0]); t8[5]=f2bf(v1[1]); t8[6]=f2bf(v1[2]); t8[7]=f2bf(v1[3]);
        *(short8*)((char*)sm.gem.aL + slotA) = *(short8*)t8;
        const unsigned short* bp = Wfull + (size_t)(tn*256 + rB)*768 + kb + kB;
        *(short8*)((char*)sm.gem.bL + slotB0) = *(const short8*)bp;
        *(short8*)((char*)sm.gem.bL + slotB1) = *(const short8*)(bp + 8);
        __syncthreads();

        short8 afr[4], bfr4[4];
#pragma unroll
        for (int mi = 0; mi < 4; ++mi)
          afr[mi]  = *(const short8*)((const char*)sm.gem.aL + (wr*4 + mi)*1024 + lane*16);
#pragma unroll
        for (int ni = 0; ni < 4; ++ni)
          bfr4[ni] = *(const short8*)((const char*)sm.gem.bL + (wc*4 + ni)*1024 + lane*16);
#pragma unroll
        for (int mi = 0; mi < 4; ++mi)
#pragma unroll
          for (int ni = 0; ni < 4; ++ni)
            acc[mi][ni] = __builtin_amdgcn_mfma_f32_16x16x32_bf16(afr[mi], bfr4[ni], acc[mi][ni], 0, 0, 0);
        __syncthreads();
      }

#pragma unroll
      for (int mi = 0; mi < 4; ++mi) {
#pragma unroll
        for (int ni = 0; ni < 4; ++ni) {
          int col = tn*256 + wc*64 + ni*16 + l15;
          float cv = cvec[col];
#pragma unroll
          for (int reg = 0; reg < 4; ++reg) {
            int row = tm*128 + wr*64 + mi*16 + lk*4 + reg;
            stg_coh(&slotp[(size_t)row*1024 + col], acc[mi][ni][reg] + cv);
          }
        }
      }
      VMCNT0();
      __syncthreads();                       // all waves' stores at LLC
      if (tid == 0) add_rlx(&done[c], 1);
    }
  }
}

// ---------------- host ----------------
extern "C" void kernel_launch(void* const* d_in, const int* in_sizes, int n_in,
                              void* d_out, int out_size, void* d_ws, size_t ws_size,
                              hipStream_t stream) {
  const float* x   = (const float*)d_in[0];
  const float* Wf  = (const float*)d_in[1];
  const float* bf_ = (const float*)d_in[2];
  const float* thf = (const float*)d_in[3];
  const float* Wi  = (const float*)d_in[4];
  const float* bi_ = (const float*)d_in[5];
  const float* thi = (const float*)d_in[6];
  const float* Wg  = (const float*)d_in[7];
  const float* bg_ = (const float*)d_in[8];
  const float* thg = (const float*)d_in[9];
  const float* Wo  = (const float*)d_in[10];
  const float* bo_ = (const float*)d_in[11];
  const float* tho = (const float*)d_in[12];
  float* out = (float*)d_out;

  char* ws = (char*)d_ws;
  unsigned short* Wfull = (unsigned short*)ws;            // 1.5 MB
  float* cvec  = (float*)(ws + 1572864);                  // 4 KB
  int*   flags = (int*)(ws + 1576960);                    // 2 KB (512 ints)
  float* ring  = (float*)(ws + 4194304);                  // RING x 8 MB = 32 MB

  prep_kernel<<<1024, 256, 0, stream>>>(Wf, Wi, Wg, Wo, bf_, bi_, bg_, bo_,
                                        thf, thi, thg, tho, Wfull, cvec, flags);
  persist_kernel<<<NWG, 512, 0, stream>>>(x, Wfull, cvec, ring,
                                          flags, flags + 128, out);
}